// Round 2
// baseline (22250.528 us; speedup 1.0000x reference)
//
#include <hip/hip_runtime.h>
#include <cmath>

// Problem constants
#define T_STEPS 512
#define BATCH   64
#define HID     1024
#define INSZ    128
#define ESZ     819
#define OSZ     64

// ws layout (floats):
//  eff_w  [1024*1024]                 @ 0
//  w_ihT  [128*1024]                  @ 1048576
//  u      [64][512][1024] ([b][t][h]) @ 1179648
//  flags  [256*32] uints              @ 34734080
//  w_fcp  [64*820] (padded w_fc)      @ 34742272
#define WS_EFFW   0
#define WS_WIHT   1048576
#define WS_U      1179648
#define WS_FLAGS  34734080
#define WS_WFCP   34742272

// ---------------- prep kernels ----------------
__global__ void prep_effw(const float* __restrict__ w_hh, const float* __restrict__ mask,
                          float* __restrict__ eff) {
    const int i = (blockIdx.x * 256 + threadIdx.x) * 4;
    const float4 w = *(const float4*)(w_hh + i);
    const float4 m = *(const float4*)(mask + i);
    float4 r;
    r.x = fabsf(w.x) * m.x; r.y = fabsf(w.y) * m.y;
    r.z = fabsf(w.z) * m.z; r.w = fabsf(w.w) * m.w;
    *(float4*)(eff + i) = r;
}

__global__ void prep_wihT(const float* __restrict__ w_ih, float* __restrict__ w_ihT) {
    const int idx = blockIdx.x * 256 + threadIdx.x;   // idx = i*1024 + h
    const int i = idx >> 10, h = idx & 1023;
    w_ihT[idx] = w_ih[h * INSZ + i];
}

__global__ void prep_wfc(const float* __restrict__ w_fc, float* __restrict__ w_fcp) {
    const int o = blockIdx.x;
    for (int e = threadIdx.x; e < 820; e += 256)
        w_fcp[o * 820 + e] = (e < ESZ) ? w_fc[o * ESZ + e] : 0.f;
}

// ---------------- input projection: u[b][t][h] = x[t,b,:]@w_ih[h,:] + b_ih[h] ----------------
__global__ void inp_proj(const float* __restrict__ x, const float* __restrict__ w_ihT,
                         const float* __restrict__ b_ih, float* __restrict__ u) {
    __shared__ float xs[INSZ * 64];   // [i][b], 32 KB
    const int t = blockIdx.x, tid = threadIdx.x;
    const float* xt = x + (size_t)t * BATCH * INSZ;
    for (int k = tid * 4; k < BATCH * INSZ; k += 1024) {
        const float4 v = *(const float4*)(xt + k);
        const int b = k >> 7, i = k & 127;
        xs[(i + 0) * 64 + b] = v.x; xs[(i + 1) * 64 + b] = v.y;
        xs[(i + 2) * 64 + b] = v.z; xs[(i + 3) * 64 + b] = v.w;
    }
    __syncthreads();
    for (int hp = 0; hp < 2; ++hp) {
        const int h = hp * 512 + tid * 2;
        const float bi0 = b_ih[h], bi1 = b_ih[h + 1];
        for (int b0 = 0; b0 < 64; b0 += 8) {
            float acc0[8], acc1[8];
#pragma unroll
            for (int bb = 0; bb < 8; ++bb) { acc0[bb] = 0.f; acc1[bb] = 0.f; }
#pragma unroll 4
            for (int i = 0; i < INSZ; ++i) {
                const float2 w2 = *(const float2*)(w_ihT + i * 1024 + h);
                const float4 xa = *(const float4*)(xs + i * 64 + b0);
                const float4 xb = *(const float4*)(xs + i * 64 + b0 + 4);
                const float xv[8] = {xa.x, xa.y, xa.z, xa.w, xb.x, xb.y, xb.z, xb.w};
#pragma unroll
                for (int bb = 0; bb < 8; ++bb) {
                    acc0[bb] = fmaf(w2.x, xv[bb], acc0[bb]);
                    acc1[bb] = fmaf(w2.y, xv[bb], acc1[bb]);
                }
            }
#pragma unroll
            for (int bb = 0; bb < 8; ++bb) {
                float2 r; r.x = acc0[bb] + bi0; r.y = acc1[bb] + bi1;
                *(float2*)(u + ((size_t)(b0 + bb) * T_STEPS + t) * 1024 + h) = r;
            }
        }
    }
}

// ---------------- persistent recurrent scan (cooperative) ----------------
// 256 WGs x 512 thr. WG = (bg = blk&7 -> 8 batches, hgrp = blk>>3 -> 32 hidden rows).
// Weights live in registers: thread (wave w, lane c) holds w[h0+4w+i][jj*64+c], i<4, jj<16.
// Partials for quad w live entirely in wave w -> in-register 64-lane butterfly reduce.
// act ([t][b][h]) is written directly to d_out; cross-WG exchange via act + per-WG flags.
__global__ void __launch_bounds__(512, 2)
rnn_scan(const float* __restrict__ eff_w, const float* __restrict__ u,
         const float* __restrict__ b_hh, const float* __restrict__ alpha,
         float* __restrict__ act, unsigned* __restrict__ flags) {
    __shared__ float pp[8192];     // prev outputs [b][j], stride-1 lane access everywhere
    __shared__ float red_s[256];   // reduced outputs, swizzled
    const int tid = threadIdx.x, wg = blockIdx.x;
    const int bg = wg & 7, hgrp = wg >> 3;
    const int h0 = hgrp << 5, b0 = bg << 3;
    const int wave = tid >> 6, c = tid & 63;

    float wreg[4][16];   // register-resident recurrent weights
    {
        const float* wr = eff_w + (size_t)(h0 + (wave << 2)) * 1024 + c;
#pragma unroll
        for (int i = 0; i < 4; ++i)
#pragma unroll
            for (int jj = 0; jj < 16; ++jj)
                wreg[i][jj] = wr[i * 1024 + (jj << 6)];
    }
    const float a = alpha[0];
    const bool owner = (tid < 256);
    const int o_h = tid & 31, o_b = (tid >> 5) & 7;   // owner (h,b) mapping, h fastest
    const int rh = h0 + o_h, rb = b0 + o_b;
    const float bias = b_hh[rh];
    const size_t u_base = ((size_t)rb * T_STEPS) * 1024 + rh;
    float state = 0.f;
    __syncthreads();

    for (int t = 0; t < T_STEPS; ++t) {
        float uval = 0.f;
        if (owner) uval = u[u_base + ((size_t)t << 10)];   // overlaps the poll
        float red = 0.f;
        if (t > 0) {
            if (wave == 0) {   // wave 0 spins on the 32 partner flags of this batch-group
                const unsigned tgt = (unsigned)t;
                for (;;) {
                    unsigned v = tgt;
                    if (c < 32)
                        v = __hip_atomic_load(flags + ((bg + (c << 3)) << 5),
                                              __ATOMIC_RELAXED, __HIP_MEMORY_SCOPE_AGENT);
                    if (__ballot(v >= tgt) == ~0ull) break;
                    __builtin_amdgcn_s_sleep(1);
                }
            }
            __syncthreads();
            {   // stage prev outputs: wave stages batch row `wave`; b32 loads/writes,
                // lane-consecutive (coalesced 256B/wave, LDS bank = c&31 -> conflict-free)
                const float* src = act + ((size_t)(t - 1) * BATCH + b0 + wave) * 1024 + c;
                float* dst = pp + (wave << 10) + c;
#pragma unroll
                for (int m = 0; m < 16; ++m) dst[m << 6] = src[m << 6];
            }
            __syncthreads();
            float val[32];
#pragma unroll
            for (int v = 0; v < 32; ++v) val[v] = 0.f;
#pragma unroll
            for (int jj = 0; jj < 16; ++jj) {
                float pv[8];
#pragma unroll
                for (int b = 0; b < 8; ++b) pv[b] = pp[(b << 10) + (jj << 6) + c];
#pragma unroll
                for (int i = 0; i < 4; ++i) {
                    const float w = wreg[i][jj];
#pragma unroll
                    for (int b = 0; b < 8; ++b)
                        val[(i << 3) + b] = fmaf(w, pv[b], val[(i << 3) + b]);
                }
            }
            // 64-lane multi-value butterfly: 32 partial sums folded in-register.
            // After 5 fold levels + 1 duplicate level, lane c holds output v=(c>>1)&31
            // (v4..v0 = c5..c1), summed over all 64 lanes.
#pragma unroll
            for (int lvl = 0; lvl < 5; ++lvl) {
                const int mask = 32 >> lvl, n = 16 >> lvl;
                const bool hi = (c & mask) != 0;
#pragma unroll
                for (int v = 0; v < n; ++v) {
                    const float send = hi ? val[v] : val[v + n];
                    const float keep = hi ? val[v + n] : val[v];
                    val[v] = keep + __shfl_xor(send, mask, 64);
                }
            }
            val[0] += __shfl_xor(val[0], 1, 64);
            if ((c & 1) == 0) {
                const int v = c >> 1, bi = v & 7, ii = v >> 3;
                const int hl = (wave << 2) + ii;
                red_s[(bi << 5) + ((hl + (bi << 2)) & 31)] = val[0];  // banks distinct/wave
            }
            __syncthreads();
            if (owner) red = red_s[(o_b << 5) + ((o_h + (o_b << 2)) & 31)];
        }
        if (owner) {
            const float tot = uval + bias + red;
            state = fmaf(a, tot - state, state);
            const float ov = tanhf(state);
            // coalesced (h fastest) agent-scope write-through store
            __hip_atomic_store(act + ((size_t)t * BATCH + rb) * 1024 + rh, ov,
                               __ATOMIC_RELAXED, __HIP_MEMORY_SCOPE_AGENT);
        }
        asm volatile("s_waitcnt vmcnt(0)" ::: "memory");
        __syncthreads();   // all waves' stores drained before the flag
        if (tid == 0)
            __hip_atomic_store(flags + (wg << 5), (unsigned)(t + 1),
                               __ATOMIC_RELAXED, __HIP_MEMORY_SCOPE_AGENT);
    }
}

// ---------------- final FC: out0[t][b][o] = act[t][b][:819]@w_fc[o,:] + b_fc[o] ----------------
__global__ void fc_out(const float* __restrict__ act, const float* __restrict__ w_fcp,
                       const float* __restrict__ b_fc, float* __restrict__ out0) {
    __shared__ float hs[16 * 820];   // 52.5 KB
    const int t = blockIdx.x >> 2, bq = blockIdx.x & 3, tid = threadIdx.x;
    const int b0 = bq << 4;
    for (int r = 0; r < 16; ++r) {
        const float* src = act + ((size_t)t * BATCH + b0 + r) * 1024;  // contiguous rows now
        for (int e = tid; e < 820; e += 256) hs[r * 820 + e] = (e < ESZ) ? src[e] : 0.f;
    }
    __syncthreads();
    const int bb = tid >> 4, ol = tid & 15;
    float acc[4] = {0.f, 0.f, 0.f, 0.f};
    const float* hrow = hs + bb * 820;
    for (int e = 0; e < 820; e += 4) {
        const float4 hv = *(const float4*)(hrow + e);
#pragma unroll
        for (int k = 0; k < 4; ++k) {
            const float4 wv = *(const float4*)(w_fcp + (size_t)(ol + (k << 4)) * 820 + e);
            acc[k] += hv.x * wv.x + hv.y * wv.y + hv.z * wv.z + hv.w * wv.w;
        }
    }
    const int b = b0 + bb;
#pragma unroll
    for (int k = 0; k < 4; ++k) {
        const int o = ol + (k << 4);
        out0[((size_t)t * BATCH + b) * OSZ + o] = acc[k] + b_fc[o];
    }
}

extern "C" void kernel_launch(void* const* d_in, const int* in_sizes, int n_in,
                              void* d_out, int out_size, void* d_ws, size_t ws_size,
                              hipStream_t stream) {
    const float* x     = (const float*)d_in[0];
    const float* w_ih  = (const float*)d_in[1];
    const float* b_ih  = (const float*)d_in[2];
    const float* w_hh  = (const float*)d_in[3];
    const float* b_hh  = (const float*)d_in[4];
    const float* w_fc  = (const float*)d_in[5];
    const float* b_fc  = (const float*)d_in[6];
    const float* alpha = (const float*)d_in[7];
    const float* mask  = (const float*)d_in[8];

    float* out  = (float*)d_out;
    float* out0 = out;                                 // [512][64][64]
    float* act  = out + (size_t)T_STEPS * BATCH * OSZ; // [512][64][1024], written by scan

    float* ws     = (float*)d_ws;
    float* eff_w  = ws + WS_EFFW;
    float* w_ihT  = ws + WS_WIHT;
    float* u      = ws + WS_U;
    unsigned* flags = (unsigned*)(ws + WS_FLAGS);
    float* w_fcp  = ws + WS_WFCP;

    hipMemsetAsync(flags, 0, 8192 * sizeof(unsigned), stream);
    prep_effw<<<1024, 256, 0, stream>>>(w_hh, mask, eff_w);
    prep_wihT<<<512, 256, 0, stream>>>(w_ih, w_ihT);
    prep_wfc<<<64, 256, 0, stream>>>(w_fc, w_fcp);
    inp_proj<<<512, 256, 0, stream>>>(x, w_ihT, b_ih, u);

    void* args[] = {(void*)&eff_w, (void*)&u, (void*)&b_hh, (void*)&alpha,
                    (void*)&act, (void*)&flags};
    hipLaunchCooperativeKernel(reinterpret_cast<const void*>(rnn_scan),
                               dim3(256), dim3(512), args, 0, stream);

    fc_out<<<2048, 256, 0, stream>>>(act, w_fcp, b_fc, out0);
}

// Round 3
// 21802.898 us; speedup vs baseline: 1.0205x; 1.0205x over previous
//
#include <hip/hip_runtime.h>
#include <cmath>

// Problem constants
#define T_STEPS 512
#define BATCH   64
#define HID     1024
#define INSZ    128
#define ESZ     819
#define OSZ     64

// ws layout (floats):
//  w_ihT [128*1024]                  @ 0
//  u     [64][512][1024] ([b][t][h]) @ 131072
//  ctr   [8*512] uints               @ 33685504
#define WS_WIHT 0
#define WS_U    131072
#define WS_CTR  33685504

// ---------------- prep: transpose w_ih ----------------
__global__ void prep_wihT(const float* __restrict__ w_ih, float* __restrict__ w_ihT) {
    const int idx = blockIdx.x * 256 + threadIdx.x;   // idx = i*1024 + h
    const int i = idx >> 10, h = idx & 1023;
    w_ihT[idx] = w_ih[h * INSZ + i];
}

// ---------------- input projection: u[b][t][h] = x[t,b,:]@w_ih[h,:] + b_ih[h] ----------------
__global__ void inp_proj(const float* __restrict__ x, const float* __restrict__ w_ihT,
                         const float* __restrict__ b_ih, float* __restrict__ u) {
    __shared__ float xs[INSZ * 64];   // [i][b], 32 KB
    const int t = blockIdx.x, tid = threadIdx.x;
    const float* xt = x + (size_t)t * BATCH * INSZ;
    for (int k = tid * 4; k < BATCH * INSZ; k += 1024) {
        const float4 v = *(const float4*)(xt + k);
        const int b = k >> 7, i = k & 127;
        xs[(i + 0) * 64 + b] = v.x; xs[(i + 1) * 64 + b] = v.y;
        xs[(i + 2) * 64 + b] = v.z; xs[(i + 3) * 64 + b] = v.w;
    }
    __syncthreads();
    for (int hp = 0; hp < 2; ++hp) {
        const int h = hp * 512 + tid * 2;
        const float bi0 = b_ih[h], bi1 = b_ih[h + 1];
        for (int b0 = 0; b0 < 64; b0 += 8) {
            float acc0[8], acc1[8];
#pragma unroll
            for (int bb = 0; bb < 8; ++bb) { acc0[bb] = 0.f; acc1[bb] = 0.f; }
#pragma unroll 4
            for (int i = 0; i < INSZ; ++i) {
                const float2 w2 = *(const float2*)(w_ihT + i * 1024 + h);
                const float4 xa = *(const float4*)(xs + i * 64 + b0);
                const float4 xb = *(const float4*)(xs + i * 64 + b0 + 4);
                const float xv[8] = {xa.x, xa.y, xa.z, xa.w, xb.x, xb.y, xb.z, xb.w};
#pragma unroll
                for (int bb = 0; bb < 8; ++bb) {
                    acc0[bb] = fmaf(w2.x, xv[bb], acc0[bb]);
                    acc1[bb] = fmaf(w2.y, xv[bb], acc1[bb]);
                }
            }
#pragma unroll
            for (int bb = 0; bb < 8; ++bb) {
                float2 r; r.x = acc0[bb] + bi0; r.y = acc1[bb] + bi1;
                *(float2*)(u + ((size_t)(b0 + bb) * T_STEPS + t) * 1024 + h) = r;
            }
        }
    }
}

// ---------------- persistent recurrent scan (cooperative), FC fused ----------------
// 256 WGs x 512 thr. WG = (bg = blk&7 -> 8 batches, hgrp = blk>>3 -> 32 hidden rows).
// eff_w computed on the fly into registers. Sync: one counter per (bg,t); producers
// atomicAdd once per WG; ONE lane per WG polls (fixes R2's memory-side poll storm).
// FC for step t-1 is computed from pp in the wait shadow after the flag release.
__global__ void __launch_bounds__(512, 2)
rnn_scan(const float* __restrict__ w_hh, const float* __restrict__ mask,
         const float* __restrict__ u, const float* __restrict__ b_hh,
         const float* __restrict__ alpha, const float* __restrict__ w_fc,
         const float* __restrict__ b_fc, float* __restrict__ act,
         float* __restrict__ out0, unsigned* __restrict__ ctr) {
    __shared__ float pp[8192];      // prev outputs [b][j]
    __shared__ float red_s[256];    // reduced outputs, swizzled
    __shared__ float wfc_s[1664];   // w_fc rows 2*hgrp, 2*hgrp+1, zero-padded to 832
    const int tid = threadIdx.x, wg = blockIdx.x;
    const int bg = wg & 7, hgrp = wg >> 3;
    const int h0 = hgrp << 5, b0 = bg << 3;
    const int wave = tid >> 6, c = tid & 63;

    float wreg[4][16];   // register-resident recurrent weights: |w_hh| * mask
    {
        const size_t base = (size_t)(h0 + (wave << 2)) * 1024 + c;
#pragma unroll
        for (int i = 0; i < 4; ++i)
#pragma unroll
            for (int jj = 0; jj < 16; ++jj) {
                const size_t idx = base + (size_t)i * 1024 + (jj << 6);
                wreg[i][jj] = fabsf(w_hh[idx]) * mask[idx];
            }
    }
    for (int k = tid; k < 1664; k += 512) {
        const int r = (k >= 832) ? 1 : 0, j = k - r * 832;
        wfc_s[k] = (j < ESZ) ? w_fc[(size_t)((hgrp << 1) + r) * ESZ + j] : 0.f;
    }
    const float a = alpha[0];
    const bool owner = (tid < 256);
    const int o_h = tid & 31, o_b = (tid >> 5) & 7;   // owner (h,b), h fastest
    const int rh = h0 + o_h, rb = b0 + o_b;
    const float bias = b_hh[rh];
    const float bfc = b_fc[(hgrp << 1) + (c >> 5)];
    const size_t u_base = ((size_t)rb * T_STEPS) * 1024 + rh;
    unsigned* const my_ctr = ctr + (bg << 9);
    float state = 0.f;
    __syncthreads();

    // FC for time tm from pp (valid whenever pp holds act[tm]); runs in the wait shadow
    auto do_fc = [&](int tm) {
        const int half = c >> 5, jl = c & 31;
        float facc = 0.f;
#pragma unroll
        for (int k = 0; k < 26; ++k) {
            const int j = jl + (k << 5);   // <= 831; wfc_s zero-padded there
            facc = fmaf(wfc_s[half * 832 + j], pp[(wave << 10) + j], facc);
        }
        facc += __shfl_xor(facc, 1, 64);
        facc += __shfl_xor(facc, 2, 64);
        facc += __shfl_xor(facc, 4, 64);
        facc += __shfl_xor(facc, 8, 64);
        facc += __shfl_xor(facc, 16, 64);
        if (jl == 0)
            out0[((size_t)tm * BATCH + b0 + wave) * OSZ + (hgrp << 1) + half] = facc + bfc;
    };

    for (int t = 0; t < T_STEPS; ++t) {
        float uval = 0.f;
        if (owner) uval = u[u_base + ((size_t)t << 10)];   // issued early, hides latency
        float red = 0.f;
        if (t > 0) {
            if (tid == 0) {   // single-lane poll: no memory-side storm
                while (__hip_atomic_load(my_ctr + (t - 1), __ATOMIC_RELAXED,
                                         __HIP_MEMORY_SCOPE_AGENT) < 32u)
                    __builtin_amdgcn_s_sleep(2);
            }
            __syncthreads();
            {   // stage prev outputs: wave stages batch row `wave`, lane-consecutive
                const float* src = act + ((size_t)(t - 1) * BATCH + b0 + wave) * 1024 + c;
                float* dst = pp + (wave << 10) + c;
#pragma unroll
                for (int m = 0; m < 16; ++m) dst[m << 6] = src[m << 6];
            }
            __syncthreads();
            float val[32];
#pragma unroll
            for (int v = 0; v < 32; ++v) val[v] = 0.f;
#pragma unroll
            for (int jj = 0; jj < 16; ++jj) {
                float pv[8];
#pragma unroll
                for (int b = 0; b < 8; ++b) pv[b] = pp[(b << 10) + (jj << 6) + c];
#pragma unroll
                for (int i = 0; i < 4; ++i) {
                    const float w = wreg[i][jj];
#pragma unroll
                    for (int b = 0; b < 8; ++b)
                        val[(i << 3) + b] = fmaf(w, pv[b], val[(i << 3) + b]);
                }
            }
            // 64-lane multi-value butterfly: 32 partials folded in-register
#pragma unroll
            for (int lvl = 0; lvl < 5; ++lvl) {
                const int mask_ = 32 >> lvl, n = 16 >> lvl;
                const bool hi = (c & mask_) != 0;
#pragma unroll
                for (int v = 0; v < n; ++v) {
                    const float send = hi ? val[v] : val[v + n];
                    const float keep = hi ? val[v + n] : val[v];
                    val[v] = keep + __shfl_xor(send, mask_, 64);
                }
            }
            val[0] += __shfl_xor(val[0], 1, 64);
            if ((c & 1) == 0) {
                const int v = c >> 1, bi = v & 7, ii = v >> 3;
                const int hl = (wave << 2) + ii;
                red_s[(bi << 5) + ((hl + (bi << 2)) & 31)] = val[0];
            }
            __syncthreads();
            if (owner) red = red_s[(o_b << 5) + ((o_h + (o_b << 2)) & 31)];
        }
        if (owner) {
            const float tot = uval + bias + red;
            state = fmaf(a, tot - state, state);
            const float ov = tanhf(state);
            __hip_atomic_store(act + ((size_t)t * BATCH + rb) * 1024 + rh, ov,
                               __ATOMIC_RELAXED, __HIP_MEMORY_SCOPE_AGENT);
        }
        asm volatile("s_waitcnt vmcnt(0)" ::: "memory");
        __syncthreads();   // all waves' stores drained before the flag
        if (tid == 0)
            __hip_atomic_fetch_add(my_ctr + t, 1u, __ATOMIC_RELAXED,
                                   __HIP_MEMORY_SCOPE_AGENT);
        if (t > 0) do_fc(t - 1);   // pp still holds act[t-1]; hides in partner wait
    }
    // tail: FC for t = 511
    if (tid == 0) {
        while (__hip_atomic_load(my_ctr + (T_STEPS - 1), __ATOMIC_RELAXED,
                                 __HIP_MEMORY_SCOPE_AGENT) < 32u)
            __builtin_amdgcn_s_sleep(2);
    }
    __syncthreads();
    {
        const float* src = act + ((size_t)(T_STEPS - 1) * BATCH + b0 + wave) * 1024 + c;
        float* dst = pp + (wave << 10) + c;
#pragma unroll
        for (int m = 0; m < 16; ++m) dst[m << 6] = src[m << 6];
    }
    __syncthreads();
    do_fc(T_STEPS - 1);
}

extern "C" void kernel_launch(void* const* d_in, const int* in_sizes, int n_in,
                              void* d_out, int out_size, void* d_ws, size_t ws_size,
                              hipStream_t stream) {
    const float* x     = (const float*)d_in[0];
    const float* w_ih  = (const float*)d_in[1];
    const float* b_ih  = (const float*)d_in[2];
    const float* w_hh  = (const float*)d_in[3];
    const float* b_hh  = (const float*)d_in[4];
    const float* w_fc  = (const float*)d_in[5];
    const float* b_fc  = (const float*)d_in[6];
    const float* alpha = (const float*)d_in[7];
    const float* mask  = (const float*)d_in[8];

    float* out  = (float*)d_out;
    float* out0 = out;                                 // [512][64][64]
    float* act  = out + (size_t)T_STEPS * BATCH * OSZ; // [512][64][1024], written by scan

    float* ws     = (float*)d_ws;
    float* w_ihT  = ws + WS_WIHT;
    float* u      = ws + WS_U;
    unsigned* ctr = (unsigned*)(ws + WS_CTR);

    hipMemsetAsync(ctr, 0, 4096 * sizeof(unsigned), stream);
    prep_wihT<<<512, 256, 0, stream>>>(w_ih, w_ihT);
    inp_proj<<<512, 256, 0, stream>>>(x, w_ihT, b_ih, u);

    void* args[] = {(void*)&w_hh, (void*)&mask, (void*)&u, (void*)&b_hh, (void*)&alpha,
                    (void*)&w_fc, (void*)&b_fc, (void*)&act, (void*)&out0, (void*)&ctr};
    hipLaunchCooperativeKernel(reinterpret_cast<const void*>(rnn_scan),
                               dim3(256), dim3(512), args, 0, stream);
}